// Round 7
// baseline (171.632 us; speedup 1.0000x reference)
//
#include <hip/hip_runtime.h>
#include <math.h>

#define L2C  1e-4
#define NITER 20

// ---- cross-lane helpers ----------------------------------------------------
__device__ __forceinline__ double rld(double v, int lane) {
    union { double d; int i[2]; } u, r; u.d = v;
    r.i[0] = __builtin_amdgcn_readlane(u.i[0], lane);
    r.i[1] = __builtin_amdgcn_readlane(u.i[1], lane);
    return r.d;
}
template <int CTRL>
__device__ __forceinline__ double dppd(double v) {
    union { double d; int i[2]; } u, r; u.d = v;
    r.i[0] = __builtin_amdgcn_update_dpp(0, u.i[0], CTRL, 0xF, 0xF, true);
    r.i[1] = __builtin_amdgcn_update_dpp(0, u.i[1], CTRL, 0xF, 0xF, true);
    return r.d;
}
// sum across each 16-lane DPP row (all lanes get the row total)
__device__ __forceinline__ double sum16d(double v) {
    v += dppd<0xB1>(v); v += dppd<0x4E>(v); v += dppd<0x124>(v); v += dppd<0x128>(v);
    return v;
}
// combine the 4 16-lane rows (butterfly -> bit-identical everywhere)
__device__ __forceinline__ double cross4d(double v) {
    v += __shfl_xor(v, 16, 64); v += __shfl_xor(v, 32, 64); return v;
}
template <int CTRL>
__device__ __forceinline__ float dppf(float v) {
    return __int_as_float(__builtin_amdgcn_update_dpp(0, __float_as_int(v), CTRL, 0xF, 0xF, true));
}
__device__ __forceinline__ float min16f(float v) {
    v = fminf(v, dppf<0xB1>(v)); v = fminf(v, dppf<0x4E>(v));
    v = fminf(v, dppf<0x124>(v)); v = fminf(v, dppf<0x128>(v));
    return v;
}
__device__ __forceinline__ float cross4minf(float v) {
    v = fminf(v, __shfl_xor(v, 16, 64)); v = fminf(v, __shfl_xor(v, 32, 64)); return v;
}
// fast fp64 reciprocal / rsqrt: fp32 seed + one fp64 Newton (~1e-14 rel err)
__device__ __forceinline__ double drcp(double d) {
    double x = (double)__builtin_amdgcn_rcpf((float)d);
    x = x * (2.0 - d * x);
    return x;
}
__device__ __forceinline__ double drsq(double d) {
    double x = (double)__builtin_amdgcn_rsqf((float)d);
    x = x * (1.5 - 0.5 * d * x * x);
    return x;
}
__device__ __forceinline__ float frcpf(float x) { return __builtin_amdgcn_rcpf(x); }

// One 64-lane wave per batch element. Lane l: q=l&15 (flow row q), r=l>>4;
// owns cells (q, 4c+r), c=0..3. Row-tail (q) and col-tail (4c+r) IP state kept
// redundantly per lane (bit-identical copies). fp64 state/residuals (fp32
// state NaN'd in rounds 4/5). Woodbury+Schur -> 16x16 Cholesky in registers.
// Aggressive sigma schedule (0.1 x2 then 0.015) — we only need the QP optimum
// (strictly convex), not the reference trajectory; exit when duality gap
// 288*mu ~ 6e-4 << 9.6e-2 threshold.
__global__ __launch_bounds__(64, 1) void emd_ip_kernel(const float* __restrict__ jets1,
                                                       const float* __restrict__ jets2,
                                                       float* __restrict__ out) {
    const int l = threadIdx.x;
    const int b = blockIdx.x;
    const int q = l & 15;
    const int r = l >> 4;

    __shared__ double invDl[16 * 17];  // C[i][j] at i*17+j (stride-17: conflict-free)
    __shared__ double Sst[16 * 17];    // Schur matrix staging
    __shared__ double Lst[16 * 17];    // Lst[a*17+b] = L[b][a]
    __shared__ double GstR[16], GstI[16];  // gp rhs staging
    __shared__ double QstR[16], QstI[16];  // qc solution staging

    const float* p1 = jets1 + b * 48;
    const float* p2 = jets2 + b * 48;

    double ax = (double)p1[3 * q], ay = (double)p1[3 * q + 1];
    double px[4];
#pragma unroll
    for (int c = 0; c < 4; c++) {
        int j = 4 * c + r;
        double d0 = ((double)p2[3 * j]     - ax) + 1e-12;
        double d1 = ((double)p2[3 * j + 1] - ay) + 1e-12;
        px[c] = sqrt(d0 * d0 + d1 * d1);
    }
    double h_rt = (double)p1[3 * q + 2];
    double h_ct[4];
#pragma unroll
    for (int c = 0; c < 4; c++) h_ct[c] = (double)p2[3 * (4 * c + r) + 2];

    double sw1 = sum16d(h_rt);
    double sw2 = sum16d((double)p2[3 * q + 2]);
    const double sB = fmin(sw1, sw2);
    const double sE = fabs(sw1 - sw2);

    double x[4] = {0, 0, 0, 0}, s[4] = {1, 1, 1, 1}, z[4] = {1, 1, 1, 1};
    double yv = 0.0;
    double s_rt = 1.0, z_rt = 1.0;
    double s_ct[4] = {1, 1, 1, 1}, z_ct[4] = {1, 1, 1, 1};

    for (int it = 0; it < NITER; ++it) {
        // ---- mu = mean(s*z) over 288 (redundant copies scaled) ----
        double mub = s[0]*z[0] + s[1]*z[1] + s[2]*z[2] + s[3]*z[3]
                   + 0.25 * (s_rt * z_rt)
                   + 0.0625 * (s_ct[0]*z_ct[0] + s_ct[1]*z_ct[1] + s_ct[2]*z_ct[2] + s_ct[3]*z_ct[3]);
        double mu = sum16d(cross4d(mub)) * (1.0 / 288.0);
        if (!(mu >= 2e-6)) break;   // gap ~ 288*mu ~ 6e-4 << 9.6e-2; also catches NaN
        double sg = (it < 2) ? 0.1 : 0.015;   // center hard first, then long-step
        double sgmu = sg * mu;

        // ---- x sums ----
        double rsx = cross4d(x[0] + x[1] + x[2] + x[3]);   // row q sum
        double txs = sum16d(rsx);
        double cs[4];
#pragma unroll
        for (int c = 0; c < 4; c++) cs[c] = sum16d(x[c]);  // col 4c+r sums
        double ra = txs - sB;

        // ---- tail residuals (lane-local) ----
        double is_rt = drcp(s_rt);
        double rp_rt = rsx + s_rt - h_rt;
        double rs_rt = s_rt * z_rt - sgmu;
        double tt_rt = (z_rt * (rsx - h_rt) + sgmu) * is_rt;
        double is_ct[4], rp_ct[4], rs_ct[4], tt_ct[4];
#pragma unroll
        for (int c = 0; c < 4; c++) {
            is_ct[c] = drcp(s_ct[c]);
            rp_ct[c] = cs[c] + s_ct[c] - h_ct[c];
            rs_ct[c] = s_ct[c] * z_ct[c] - sgmu;
            tt_ct[c] = (z_ct[c] * (cs[c] - h_ct[c]) + sgmu) * is_ct[c];
        }

        // ---- cell residuals ----
        double rp[4], rs[4], iD[4], r1[4], rD1[4], is_[4];
#pragma unroll
        for (int c = 0; c < 4; c++) {
            is_[c] = drcp(s[c]);
            double rx = L2C * x[c] + px[c] + (-z[c] + z_rt + z_ct[c]) + yv;
            rp[c] = s[c] - x[c];
            rs[c] = s[c] * z[c] - sgmu;
            double tk = (sgmu - z[c] * x[c]) * is_[c];   // (z*rp - rs)/s
            iD[c] = drcp(L2C + z[c] * is_[c]);
            r1[c] = rx - tk + tt_rt + tt_ct[c];
            rD1[c] = r1[c] * iD[c];
            invDl[q * 17 + 4 * c + r] = iD[c];
        }

        // ---- sums of invD, rD1 ----
        double rsI = cross4d(iD[0] + iD[1] + iD[2] + iD[3]);
        double rsR = cross4d(rD1[0] + rD1[1] + rD1[2] + rD1[3]);
        double csI[4], csR[4];
#pragma unroll
        for (int c = 0; c < 4; c++) { csI[c] = sum16d(iD[c]); csR[c] = sum16d(rD1[c]); }

        double ar = drcp(s_rt * drcp(z_rt) + rsI);   // 1/A_q
        double aR = ar * rsR;
        double aI = ar * rsI;

        // ---- rhs gp[j] = g_c[j] - sum_i aX_i*C[i][j] (DPP row reduction) ----
        double gpR[4], gpI[4], bb[4];
#pragma unroll
        for (int c = 0; c < 4; c++) {
            gpR[c] = csR[c] - sum16d(aR * iD[c]);
            gpI[c] = csI[c] - sum16d(aI * iD[c]);
            bb[c]  = s_ct[c] * drcp(z_ct[c]) + csI[c];
            if (q == 4 * c + r) { GstR[q] = gpR[c]; GstI[q] = gpI[c]; }  // stage
        }

        // ---- Schur S[q][4c+r] = diag - sum_t ar_t C[t][q] C[t][4c+r] ----
        double accS[4] = {0, 0, 0, 0};
#pragma unroll
        for (int t = 0; t < 16; t++) {
            double w = rld(ar, t) * invDl[t * 17 + q];
#pragma unroll
            for (int c = 0; c < 4; c++) accS[c] += w * invDl[t * 17 + 4 * c + r];
        }
#pragma unroll
        for (int c = 0; c < 4; c++)
            Sst[q * 17 + 4 * c + r] = ((q == 4 * c + r) ? bb[c] : 0.0) - accS[c];

        // ---- load S row q from LDS ----
        double Sr[16];
#pragma unroll
        for (int j2 = 0; j2 < 16; j2++) Sr[j2] = Sst[q * 17 + j2];
        double D0own = Sr[q];

        // ---- 16x16 Cholesky in registers; columns staged to LDS ----
        double invdv = 0.0;
#pragma unroll
        for (int kk = 0; kk < 16; kk++) {
            double flo = fmax(1e-12 * fabs(rld(D0own, kk)), 1e-280);
            double dkk = fmax(rld(Sr[kk], kk), flo);
            double inv = drsq(dkk);
            invdv = (q == kk) ? inv : invdv;
            double Lc = Sr[kk] * inv;      // L[q][kk] (valid q>=kk)
            Sr[kk] = Lc;
            if (l < 16) Lst[kk * 17 + l] = Lc;
#pragma unroll
            for (int jj = kk + 1; jj < 16; jj++)
                Sr[jj] -= Lc * rld(Lc, jj);
        }

        // ---- gather rhs + L^T row from LDS ----
        double y1 = GstR[q], y2 = GstI[q];
        double LTr[16];
#pragma unroll
        for (int kk = 0; kk < 16; kk++) LTr[kk] = Lst[q * 17 + kk];  // L[kk][q]

        // ---- forward solve L y = gp ----
#pragma unroll
        for (int kk = 0; kk < 16; kk++) {
            double inv = rld(invdv, kk);
            double t1 = rld(y1, kk) * inv;
            double t2 = rld(y2, kk) * inv;
            if (q == kk)      { y1 = t1; y2 = t2; }
            else if (q > kk)  { y1 -= Sr[kk] * t1; y2 -= Sr[kk] * t2; }
        }
        // ---- backward solve L^T qc = y ----
#pragma unroll
        for (int kk = 15; kk >= 0; kk--) {
            double inv = rld(invdv, kk);
            double t1 = rld(y1, kk) * inv;
            double t2 = rld(y2, kk) * inv;
            if (q == kk)      { y1 = t1; y2 = t2; }
            else if (q < kk)  { y1 -= LTr[kk] * t1; y2 -= LTr[kk] * t2; }
        }
        // y1,y2 = qc[q] (identical across r-groups)

        // ---- stage qc, gather per own columns ----
        if (l < 16) { QstR[l] = y1; QstI[l] = y2; }
        double qc1c[4], qcvc[4];
#pragma unroll
        for (int c = 0; c < 4; c++) { qc1c[c] = QstR[4 * c + r]; qcvc[c] = QstI[4 * c + r]; }

        // ---- qr = ar*(g_r - sum_j C[q][j] qc_j) (cross4 reduction) ----
        double pr1 = iD[0]*qc1c[0] + iD[1]*qc1c[1] + iD[2]*qc1c[2] + iD[3]*qc1c[3];
        double prv = iD[0]*qcvc[0] + iD[1]*qcvc[1] + iD[2]*qcvc[2] + iD[3]*qcvc[3];
        double qr1 = ar * (rsR - cross4d(pr1));
        double qrv = ar * (rsI - cross4d(prv));

        // ---- u = H^{-1} r1, v = H^{-1} 1 ----
        double u[4], v[4];
#pragma unroll
        for (int c = 0; c < 4; c++) {
            u[c] = (r1[c] - qr1 - qc1c[c]) * iD[c];
            v[c] = (1.0  - qrv - qcvc[c]) * iD[c];
        }
        double usum = sum16d(cross4d(u[0] + u[1] + u[2] + u[3]));
        double vsum = sum16d(cross4d(v[0] + v[1] + v[2] + v[3]));
        double dy = (ra - usum) * drcp(vsum);

        // ---- dx + sums ----
        double dx[4];
#pragma unroll
        for (int c = 0; c < 4; c++) dx[c] = -u[c] - v[c] * dy;
        double rsdx = cross4d(dx[0] + dx[1] + dx[2] + dx[3]);
        double csdx[4];
#pragma unroll
        for (int c = 0; c < 4; c++) csdx[c] = sum16d(dx[c]);

        // ---- ds, dz (fp64); ratio tests fp32 (0.99 margin >> 3e-7 error) ----
        float am = 1e30f;
        double ds[4], dz[4];
#pragma unroll
        for (int c = 0; c < 4; c++) {
            ds[c] = dx[c] - rp[c];
            dz[c] = -(rs[c] + z[c] * ds[c]) * is_[c];
            if (ds[c] < 0.0) am = fminf(am, (float)s[c] * frcpf((float)(-ds[c])));
            if (dz[c] < 0.0) am = fminf(am, (float)z[c] * frcpf((float)(-dz[c])));
        }
        double ds_rt = -rp_rt - rsdx;
        double dz_rt = -(rs_rt + z_rt * ds_rt) * is_rt;
        if (ds_rt < 0.0) am = fminf(am, (float)s_rt * frcpf((float)(-ds_rt)));
        if (dz_rt < 0.0) am = fminf(am, (float)z_rt * frcpf((float)(-dz_rt)));
        double ds_ct[4], dz_ct[4];
#pragma unroll
        for (int c = 0; c < 4; c++) {
            ds_ct[c] = -rp_ct[c] - csdx[c];
            dz_ct[c] = -(rs_ct[c] + z_ct[c] * ds_ct[c]) * is_ct[c];
            if (ds_ct[c] < 0.0) am = fminf(am, (float)s_ct[c] * frcpf((float)(-ds_ct[c])));
            if (dz_ct[c] < 0.0) am = fminf(am, (float)z_ct[c] * frcpf((float)(-dz_ct[c])));
        }
        float amin = min16f(cross4minf(am));
        double alpha = 0.99 * fmin(1.0, (double)amin);
        alpha = ((dy - dy) == 0.0) ? alpha : 0.0;   // freeze on garbage direction

        // ---- step ----
#pragma unroll
        for (int c = 0; c < 4; c++) {
            x[c] += alpha * dx[c];
            s[c] += alpha * ds[c];
            z[c] += alpha * dz[c];
            s_ct[c] += alpha * ds_ct[c];
            z_ct[c] += alpha * dz_ct[c];
        }
        yv += alpha * dy;
        s_rt += alpha * ds_rt;
        z_rt += alpha * dz_rt;
    }

    // ---- emd = p.x + |sum w1 - sum w2| ----
    double e = sum16d(cross4d(px[0]*x[0] + px[1]*x[1] + px[2]*x[2] + px[3]*x[3]));
    if (l == 0) out[b] = (float)(e + sE);
}

extern "C" void kernel_launch(void* const* d_in, const int* in_sizes, int n_in,
                              void* d_out, int out_size, void* d_ws, size_t ws_size,
                              hipStream_t stream) {
    const float* jets1 = (const float*)d_in[0];
    const float* jets2 = (const float*)d_in[1];
    float* out = (float*)d_out;
    int B = in_sizes[0] / 48;   // 32
    emd_ip_kernel<<<dim3(B), dim3(64), 0, stream>>>(jets1, jets2, out);
}

// Round 11
// 147.570 us; speedup vs baseline: 1.1631x; 1.1631x over previous
//
#include <hip/hip_runtime.h>
#include <math.h>

#define L2C  1e-4
#define SIGC 0.1
#define NITER 20

// ---- cross-lane helpers ----------------------------------------------------
__device__ __forceinline__ double rld(double v, int lane) {
    union { double d; int i[2]; } u, r; u.d = v;
    r.i[0] = __builtin_amdgcn_readlane(u.i[0], lane);
    r.i[1] = __builtin_amdgcn_readlane(u.i[1], lane);
    return r.d;
}
template <int CTRL>
__device__ __forceinline__ double dppd(double v) {
    union { double d; int i[2]; } u, r; u.d = v;
    r.i[0] = __builtin_amdgcn_update_dpp(0, u.i[0], CTRL, 0xF, 0xF, true);
    r.i[1] = __builtin_amdgcn_update_dpp(0, u.i[1], CTRL, 0xF, 0xF, true);
    return r.d;
}
// sum across each 16-lane DPP row (all lanes get the row total)
__device__ __forceinline__ double sum16d(double v) {
    v += dppd<0xB1>(v); v += dppd<0x4E>(v); v += dppd<0x124>(v); v += dppd<0x128>(v);
    return v;
}
// combine the 4 16-lane rows (butterfly -> bit-identical everywhere)
__device__ __forceinline__ double cross4d(double v) {
    v += __shfl_xor(v, 16, 64); v += __shfl_xor(v, 32, 64); return v;
}
template <int CTRL>
__device__ __forceinline__ float dppf(float v) {
    return __int_as_float(__builtin_amdgcn_update_dpp(0, __float_as_int(v), CTRL, 0xF, 0xF, true));
}
__device__ __forceinline__ float min16f(float v) {
    v = fminf(v, dppf<0xB1>(v)); v = fminf(v, dppf<0x4E>(v));
    v = fminf(v, dppf<0x124>(v)); v = fminf(v, dppf<0x128>(v));
    return v;
}
__device__ __forceinline__ float cross4minf(float v) {
    v = fminf(v, __shfl_xor(v, 16, 64)); v = fminf(v, __shfl_xor(v, 32, 64)); return v;
}
// fast fp64 reciprocal / rsqrt: fp32 seed + one fp64 Newton (~1e-14 rel err)
__device__ __forceinline__ double drcp(double d) {
    double x = (double)__builtin_amdgcn_rcpf((float)d);
    x = x * (2.0 - d * x);
    return x;
}
__device__ __forceinline__ double drsq(double d) {
    double x = (double)__builtin_amdgcn_rsqf((float)d);
    x = x * (1.5 - 0.5 * d * x * x);
    return x;
}
__device__ __forceinline__ float frcpf(float x) { return __builtin_amdgcn_rcpf(x); }

// One 64-lane wave per batch element. Lane l: q=l&15 (flow row q), r=l>>4;
// owns cells (q, 4c+r), c=0..3. Row-tail (q) and col-tail (4c+r) IP state
// redundant per lane. fp64 state (fp32 state NaN'd r4/r5; Mehrotra stalled
// r8/r9/r10 — this is the proven r6 fixed-sigma structure). Woodbury+Schur ->
// 16x16 register Cholesky. New vs r6: (a) exit at mu<3e-5 (gap ~ 8.6e-3,
// 11x under threshold), (b) rsx/cs/ra maintained INCREMENTALLY (linear in x;
// update terms already computed for the step) — removes 6 wave reductions
// from the top of every iteration.
__global__ __launch_bounds__(64, 1) void emd_ip_kernel(const float* __restrict__ jets1,
                                                       const float* __restrict__ jets2,
                                                       float* __restrict__ out) {
    const int l = threadIdx.x;
    const int b = blockIdx.x;
    const int q = l & 15;
    const int r = l >> 4;

    __shared__ double invDl[16 * 17];      // C[i][j] at i*17+j (stride-17: conflict-free)
    __shared__ double Sst[16 * 17];        // Schur staging
    __shared__ double Lst[16 * 17];        // Lst[a*17+b] = L[b][a]
    __shared__ double GstR[16], GstI[16];  // rhs staging
    __shared__ double QstR[16], QstI[16];  // solution staging

    const float* p1 = jets1 + b * 48;
    const float* p2 = jets2 + b * 48;

    double ax = (double)p1[3 * q], ay = (double)p1[3 * q + 1];
    double px[4];
#pragma unroll
    for (int c = 0; c < 4; c++) {
        int j = 4 * c + r;
        double d0 = ((double)p2[3 * j]     - ax) + 1e-12;
        double d1 = ((double)p2[3 * j + 1] - ay) + 1e-12;
        px[c] = sqrt(d0 * d0 + d1 * d1);
    }
    double h_rt = (double)p1[3 * q + 2];
    double h_ct[4];
#pragma unroll
    for (int c = 0; c < 4; c++) h_ct[c] = (double)p2[3 * (4 * c + r) + 2];

    double sw1 = sum16d(h_rt);
    double sw2 = sum16d((double)p2[3 * q + 2]);
    const double sB = fmin(sw1, sw2);
    const double sE = fabs(sw1 - sw2);

    double x[4] = {0, 0, 0, 0}, s[4] = {1, 1, 1, 1}, z[4] = {1, 1, 1, 1};
    double yv = 0.0;
    double s_rt = 1.0, z_rt = 1.0;
    double s_ct[4] = {1, 1, 1, 1}, z_ct[4] = {1, 1, 1, 1};
    // incrementally-maintained sums of x (x starts at 0)
    double rsx = 0.0;                      // row-q sum of x
    double cs[4] = {0, 0, 0, 0};           // col 4c+r sums of x
    double ra = -sB;                       // sum(x) - sB

    for (int it = 0; it < NITER; ++it) {
        // ---- mu = mean(s*z) over 288 (redundant copies scaled) ----
        double mub = s[0]*z[0] + s[1]*z[1] + s[2]*z[2] + s[3]*z[3]
                   + 0.25 * (s_rt * z_rt)
                   + 0.0625 * (s_ct[0]*z_ct[0] + s_ct[1]*z_ct[1] + s_ct[2]*z_ct[2] + s_ct[3]*z_ct[3]);
        double mu = sum16d(cross4d(mub)) * (1.0 / 288.0);
        if (!(mu >= 3e-5)) break;   // gap ~ 288*mu ~ 8.6e-3 << 9.6e-2; catches NaN
        double sgmu = SIGC * mu;

        // ---- tail residuals (lane-local; rsx/cs maintained incrementally) ----
        double is_rt = drcp(s_rt);
        double rp_rt = rsx + s_rt - h_rt;
        double rs_rt = s_rt * z_rt - sgmu;
        double tt_rt = (z_rt * (rsx - h_rt) + sgmu) * is_rt;
        double is_ct[4], rp_ct[4], rs_ct[4], tt_ct[4];
#pragma unroll
        for (int c = 0; c < 4; c++) {
            is_ct[c] = drcp(s_ct[c]);
            rp_ct[c] = cs[c] + s_ct[c] - h_ct[c];
            rs_ct[c] = s_ct[c] * z_ct[c] - sgmu;
            tt_ct[c] = (z_ct[c] * (cs[c] - h_ct[c]) + sgmu) * is_ct[c];
        }

        // ---- cell residuals ----
        double rp[4], rs[4], iD[4], r1[4], rD1[4], is_[4];
#pragma unroll
        for (int c = 0; c < 4; c++) {
            is_[c] = drcp(s[c]);
            double rx = L2C * x[c] + px[c] + (-z[c] + z_rt + z_ct[c]) + yv;
            rp[c] = s[c] - x[c];
            rs[c] = s[c] * z[c] - sgmu;
            double tk = (sgmu - z[c] * x[c]) * is_[c];   // (z*rp - rs)/s
            iD[c] = drcp(L2C + z[c] * is_[c]);
            r1[c] = rx - tk + tt_rt + tt_ct[c];
            rD1[c] = r1[c] * iD[c];
            invDl[q * 17 + 4 * c + r] = iD[c];
        }

        // ---- sums of invD, rD1 ----
        double rsI = cross4d(iD[0] + iD[1] + iD[2] + iD[3]);
        double rsR = cross4d(rD1[0] + rD1[1] + rD1[2] + rD1[3]);
        double csI[4], csR[4];
#pragma unroll
        for (int c = 0; c < 4; c++) { csI[c] = sum16d(iD[c]); csR[c] = sum16d(rD1[c]); }

        double ar = drcp(s_rt * drcp(z_rt) + rsI);   // 1/A_q
        double aR = ar * rsR;
        double aI = ar * rsI;

        // ---- rhs gp[j] = g_c[j] - sum_i aX_i*C[i][j] (DPP row reduction) ----
        double gpR[4], gpI[4], bb[4];
#pragma unroll
        for (int c = 0; c < 4; c++) {
            gpR[c] = csR[c] - sum16d(aR * iD[c]);
            gpI[c] = csI[c] - sum16d(aI * iD[c]);
            bb[c]  = s_ct[c] * drcp(z_ct[c]) + csI[c];
            if (q == 4 * c + r) { GstR[q] = gpR[c]; GstI[q] = gpI[c]; }  // stage
        }

        // ---- Schur S[q][4c+r] = diag - sum_t ar_t C[t][q] C[t][4c+r] ----
        double accS[4] = {0, 0, 0, 0};
#pragma unroll
        for (int t = 0; t < 16; t++) {
            double w = rld(ar, t) * invDl[t * 17 + q];
#pragma unroll
            for (int c = 0; c < 4; c++) accS[c] += w * invDl[t * 17 + 4 * c + r];
        }
#pragma unroll
        for (int c = 0; c < 4; c++)
            Sst[q * 17 + 4 * c + r] = ((q == 4 * c + r) ? bb[c] : 0.0) - accS[c];

        // ---- load S row q from LDS ----
        double Sr[16];
#pragma unroll
        for (int j2 = 0; j2 < 16; j2++) Sr[j2] = Sst[q * 17 + j2];
        double D0own = Sr[q];

        // ---- 16x16 Cholesky in registers; columns staged to LDS ----
        double invdv = 0.0;
#pragma unroll
        for (int kk = 0; kk < 16; kk++) {
            double flo = fmax(1e-12 * fabs(rld(D0own, kk)), 1e-280);
            double dkk = fmax(rld(Sr[kk], kk), flo);
            double inv = drsq(dkk);
            invdv = (q == kk) ? inv : invdv;
            double Lc = Sr[kk] * inv;      // L[q][kk] (valid q>=kk)
            Sr[kk] = Lc;
            if (l < 16) Lst[kk * 17 + l] = Lc;
#pragma unroll
            for (int jj = kk + 1; jj < 16; jj++)
                Sr[jj] -= Lc * rld(Lc, jj);
        }

        // ---- gather rhs + L^T row from LDS ----
        double y1 = GstR[q], y2 = GstI[q];
        double LTr[16];
#pragma unroll
        for (int kk = 0; kk < 16; kk++) LTr[kk] = Lst[q * 17 + kk];  // L[kk][q]

        // ---- forward solve L y = gp ----
#pragma unroll
        for (int kk = 0; kk < 16; kk++) {
            double inv = rld(invdv, kk);
            double t1 = rld(y1, kk) * inv;
            double t2 = rld(y2, kk) * inv;
            if (q == kk)      { y1 = t1; y2 = t2; }
            else if (q > kk)  { y1 -= Sr[kk] * t1; y2 -= Sr[kk] * t2; }
        }
        // ---- backward solve L^T qc = y ----
#pragma unroll
        for (int kk = 15; kk >= 0; kk--) {
            double inv = rld(invdv, kk);
            double t1 = rld(y1, kk) * inv;
            double t2 = rld(y2, kk) * inv;
            if (q == kk)      { y1 = t1; y2 = t2; }
            else if (q < kk)  { y1 -= LTr[kk] * t1; y2 -= LTr[kk] * t2; }
        }
        // y1,y2 = qc[q] (identical across r-groups)

        // ---- stage qc, gather per own columns ----
        if (l < 16) { QstR[l] = y1; QstI[l] = y2; }
        double qc1c[4], qcvc[4];
#pragma unroll
        for (int c = 0; c < 4; c++) { qc1c[c] = QstR[4 * c + r]; qcvc[c] = QstI[4 * c + r]; }

        // ---- qr = ar*(g_r - sum_j C[q][j] qc_j) (cross4 reduction) ----
        double pr1 = iD[0]*qc1c[0] + iD[1]*qc1c[1] + iD[2]*qc1c[2] + iD[3]*qc1c[3];
        double prv = iD[0]*qcvc[0] + iD[1]*qcvc[1] + iD[2]*qcvc[2] + iD[3]*qcvc[3];
        double qr1 = ar * (rsR - cross4d(pr1));
        double qrv = ar * (rsI - cross4d(prv));

        // ---- u = H^{-1} r1, v = H^{-1} 1 ----
        double u[4], v[4];
#pragma unroll
        for (int c = 0; c < 4; c++) {
            u[c] = (r1[c] - qr1 - qc1c[c]) * iD[c];
            v[c] = (1.0  - qrv - qcvc[c]) * iD[c];
        }
        double usum = sum16d(cross4d(u[0] + u[1] + u[2] + u[3]));
        double vsum = sum16d(cross4d(v[0] + v[1] + v[2] + v[3]));
        double dy = (ra - usum) * drcp(vsum);

        // ---- dx + sums ----
        double dx[4];
#pragma unroll
        for (int c = 0; c < 4; c++) dx[c] = -u[c] - v[c] * dy;
        double rsdx = cross4d(dx[0] + dx[1] + dx[2] + dx[3]);
        double csdx[4];
#pragma unroll
        for (int c = 0; c < 4; c++) csdx[c] = sum16d(dx[c]);
        double sumdx = -usum - vsum * dy;   // sum over all cells of dx (exact identity)

        // ---- ds, dz (fp64); ratio tests fp32 (0.99 margin >> 3e-7 error) ----
        float am = 1e30f;
        double ds[4], dz[4];
#pragma unroll
        for (int c = 0; c < 4; c++) {
            ds[c] = dx[c] - rp[c];
            dz[c] = -(rs[c] + z[c] * ds[c]) * is_[c];
            if (ds[c] < 0.0) am = fminf(am, (float)s[c] * frcpf((float)(-ds[c])));
            if (dz[c] < 0.0) am = fminf(am, (float)z[c] * frcpf((float)(-dz[c])));
        }
        double ds_rt = -rp_rt - rsdx;
        double dz_rt = -(rs_rt + z_rt * ds_rt) * is_rt;
        if (ds_rt < 0.0) am = fminf(am, (float)s_rt * frcpf((float)(-ds_rt)));
        if (dz_rt < 0.0) am = fminf(am, (float)z_rt * frcpf((float)(-dz_rt)));
        double ds_ct[4], dz_ct[4];
#pragma unroll
        for (int c = 0; c < 4; c++) {
            ds_ct[c] = -rp_ct[c] - csdx[c];
            dz_ct[c] = -(rs_ct[c] + z_ct[c] * ds_ct[c]) * is_ct[c];
            if (ds_ct[c] < 0.0) am = fminf(am, (float)s_ct[c] * frcpf((float)(-ds_ct[c])));
            if (dz_ct[c] < 0.0) am = fminf(am, (float)z_ct[c] * frcpf((float)(-dz_ct[c])));
        }
        float amin = min16f(cross4minf(am));
        double alpha = 0.99 * fmin(1.0, (double)amin);
        alpha = ((dy - dy) == 0.0) ? alpha : 0.0;   // freeze on garbage direction

        // ---- step (sums of x updated incrementally — all terms wave-consistent) ----
#pragma unroll
        for (int c = 0; c < 4; c++) {
            x[c] += alpha * dx[c];
            s[c] += alpha * ds[c];
            z[c] += alpha * dz[c];
            s_ct[c] += alpha * ds_ct[c];
            z_ct[c] += alpha * dz_ct[c];
            cs[c] += alpha * csdx[c];
        }
        yv += alpha * dy;
        s_rt += alpha * ds_rt;
        z_rt += alpha * dz_rt;
        rsx += alpha * rsdx;
        ra  += alpha * sumdx;
    }

    // ---- emd = p.x + |sum w1 - sum w2| ----
    double e = sum16d(cross4d(px[0]*x[0] + px[1]*x[1] + px[2]*x[2] + px[3]*x[3]));
    if (l == 0) out[b] = (float)(e + sE);
}

extern "C" void kernel_launch(void* const* d_in, const int* in_sizes, int n_in,
                              void* d_out, int out_size, void* d_ws, size_t ws_size,
                              hipStream_t stream) {
    const float* jets1 = (const float*)d_in[0];
    const float* jets2 = (const float*)d_in[1];
    float* out = (float*)d_out;
    int B = in_sizes[0] / 48;   // 32
    emd_ip_kernel<<<dim3(B), dim3(64), 0, stream>>>(jets1, jets2, out);
}

// Round 12
// 117.293 us; speedup vs baseline: 1.4633x; 1.2581x over previous
//
#include <hip/hip_runtime.h>
#include <math.h>

#define L2C  1e-4
#define SIGC 0.1
#define NITER 20

// ---- cross-lane helpers ----------------------------------------------------
__device__ __forceinline__ double rld(double v, int lane) {
    union { double d; int i[2]; } u, r; u.d = v;
    r.i[0] = __builtin_amdgcn_readlane(u.i[0], lane);
    r.i[1] = __builtin_amdgcn_readlane(u.i[1], lane);
    return r.d;
}
template <int CTRL>
__device__ __forceinline__ double dppd(double v) {
    union { double d; int i[2]; } u, r; u.d = v;
    r.i[0] = __builtin_amdgcn_update_dpp(0, u.i[0], CTRL, 0xF, 0xF, true);
    r.i[1] = __builtin_amdgcn_update_dpp(0, u.i[1], CTRL, 0xF, 0xF, true);
    return r.d;
}
// sum across each 16-lane DPP row (all lanes get the row total)
__device__ __forceinline__ double sum16d(double v) {
    v += dppd<0xB1>(v); v += dppd<0x4E>(v); v += dppd<0x124>(v); v += dppd<0x128>(v);
    return v;
}
// combine the 4 16-lane rows (butterfly -> bit-identical everywhere)
__device__ __forceinline__ double cross4d(double v) {
    v += __shfl_xor(v, 16, 64); v += __shfl_xor(v, 32, 64); return v;
}
template <int CTRL>
__device__ __forceinline__ float dppf(float v) {
    return __int_as_float(__builtin_amdgcn_update_dpp(0, __float_as_int(v), CTRL, 0xF, 0xF, true));
}
__device__ __forceinline__ float min16f(float v) {
    v = fminf(v, dppf<0xB1>(v)); v = fminf(v, dppf<0x4E>(v));
    v = fminf(v, dppf<0x124>(v)); v = fminf(v, dppf<0x128>(v));
    return v;
}
__device__ __forceinline__ float cross4minf(float v) {
    v = fminf(v, __shfl_xor(v, 16, 64)); v = fminf(v, __shfl_xor(v, 32, 64)); return v;
}
// fast fp64 reciprocal: fp32 seed + one fp64 Newton (~1e-14 rel err)
__device__ __forceinline__ double drcp(double d) {
    double x = (double)__builtin_amdgcn_rcpf((float)d);
    x = x * (2.0 - d * x);
    return x;
}
__device__ __forceinline__ float frcpf(float x) { return __builtin_amdgcn_rcpf(x); }

// One 64-lane wave per batch element. Lane l: q=l&15 (flow row q), r=l>>4;
// owns cells (q, 4c+r), c=0..3. Row-tail (q) and col-tail (4c+r) IP state
// redundant per lane. fp64 state, fixed sigma=0.1 (the r6-proven numerics;
// fp32 state NaN'd r4/r5, Mehrotra stalled r8-r10). Woodbury+Schur -> 16x16
// register LDLT (unit-L: triangular solves lose the pivot readlane + muls;
// D-divide is one lane-local mul). New vs r11: SEPARATE primal/dual step
// lengths (alpha_p over ds, alpha_d over dz — one blocking dual no longer
// throttles the primal step) and exit at mu<1e-4 (gap ~ 2.9e-2 < 9.6e-2/2).
__global__ __launch_bounds__(64, 1) void emd_ip_kernel(const float* __restrict__ jets1,
                                                       const float* __restrict__ jets2,
                                                       float* __restrict__ out) {
    const int l = threadIdx.x;
    const int b = blockIdx.x;
    const int q = l & 15;
    const int r = l >> 4;

    __shared__ double invDl[16 * 17];      // C[i][j] at i*17+j (stride-17: conflict-free)
    __shared__ double Sst[16 * 17];        // Schur staging
    __shared__ double Lst[16 * 17];        // Lst[a*17+b] = L[b][a] (unit-diag L)
    __shared__ double GstR[16], GstI[16];  // rhs staging
    __shared__ double QstR[16], QstI[16];  // solution staging

    const float* p1 = jets1 + b * 48;
    const float* p2 = jets2 + b * 48;

    double ax = (double)p1[3 * q], ay = (double)p1[3 * q + 1];
    double px[4];
#pragma unroll
    for (int c = 0; c < 4; c++) {
        int j = 4 * c + r;
        double d0 = ((double)p2[3 * j]     - ax) + 1e-12;
        double d1 = ((double)p2[3 * j + 1] - ay) + 1e-12;
        px[c] = sqrt(d0 * d0 + d1 * d1);
    }
    double h_rt = (double)p1[3 * q + 2];
    double h_ct[4];
#pragma unroll
    for (int c = 0; c < 4; c++) h_ct[c] = (double)p2[3 * (4 * c + r) + 2];

    double sw1 = sum16d(h_rt);
    double sw2 = sum16d((double)p2[3 * q + 2]);
    const double sB = fmin(sw1, sw2);
    const double sE = fabs(sw1 - sw2);

    double x[4] = {0, 0, 0, 0}, s[4] = {1, 1, 1, 1}, z[4] = {1, 1, 1, 1};
    double yv = 0.0;
    double s_rt = 1.0, z_rt = 1.0;
    double s_ct[4] = {1, 1, 1, 1}, z_ct[4] = {1, 1, 1, 1};
    // incrementally-maintained sums of x (x starts at 0)
    double rsx = 0.0;                      // row-q sum of x
    double cs[4] = {0, 0, 0, 0};           // col 4c+r sums of x
    double ra = -sB;                       // sum(x) - sB

    for (int it = 0; it < NITER; ++it) {
        // ---- mu = mean(s*z) over 288 (redundant copies scaled) ----
        double mub = s[0]*z[0] + s[1]*z[1] + s[2]*z[2] + s[3]*z[3]
                   + 0.25 * (s_rt * z_rt)
                   + 0.0625 * (s_ct[0]*z_ct[0] + s_ct[1]*z_ct[1] + s_ct[2]*z_ct[2] + s_ct[3]*z_ct[3]);
        double mu = sum16d(cross4d(mub)) * (1.0 / 288.0);
        if (!(mu >= 1e-4)) break;   // gap ~ 288*mu ~ 2.9e-2 < 9.6e-2/2; catches NaN
        double sgmu = SIGC * mu;

        // ---- tail residuals (lane-local; rsx/cs maintained incrementally) ----
        double is_rt = drcp(s_rt);
        double rp_rt = rsx + s_rt - h_rt;
        double rs_rt = s_rt * z_rt - sgmu;
        double tt_rt = (z_rt * (rsx - h_rt) + sgmu) * is_rt;
        double is_ct[4], rp_ct[4], rs_ct[4], tt_ct[4];
#pragma unroll
        for (int c = 0; c < 4; c++) {
            is_ct[c] = drcp(s_ct[c]);
            rp_ct[c] = cs[c] + s_ct[c] - h_ct[c];
            rs_ct[c] = s_ct[c] * z_ct[c] - sgmu;
            tt_ct[c] = (z_ct[c] * (cs[c] - h_ct[c]) + sgmu) * is_ct[c];
        }

        // ---- cell residuals ----
        double rp[4], rs[4], iD[4], r1[4], rD1[4], is_[4];
#pragma unroll
        for (int c = 0; c < 4; c++) {
            is_[c] = drcp(s[c]);
            double rx = L2C * x[c] + px[c] + (-z[c] + z_rt + z_ct[c]) + yv;
            rp[c] = s[c] - x[c];
            rs[c] = s[c] * z[c] - sgmu;
            double tk = (sgmu - z[c] * x[c]) * is_[c];   // (z*rp - rs)/s
            iD[c] = drcp(L2C + z[c] * is_[c]);
            r1[c] = rx - tk + tt_rt + tt_ct[c];
            rD1[c] = r1[c] * iD[c];
            invDl[q * 17 + 4 * c + r] = iD[c];
        }

        // ---- sums of invD, rD1 ----
        double rsI = cross4d(iD[0] + iD[1] + iD[2] + iD[3]);
        double rsR = cross4d(rD1[0] + rD1[1] + rD1[2] + rD1[3]);
        double csI[4], csR[4];
#pragma unroll
        for (int c = 0; c < 4; c++) { csI[c] = sum16d(iD[c]); csR[c] = sum16d(rD1[c]); }

        double ar = drcp(s_rt * drcp(z_rt) + rsI);   // 1/A_q
        double aR = ar * rsR;
        double aI = ar * rsI;

        // ---- rhs gp[j] = g_c[j] - sum_i aX_i*C[i][j] (DPP row reduction) ----
        double gpR[4], gpI[4], bb[4];
#pragma unroll
        for (int c = 0; c < 4; c++) {
            gpR[c] = csR[c] - sum16d(aR * iD[c]);
            gpI[c] = csI[c] - sum16d(aI * iD[c]);
            bb[c]  = s_ct[c] * drcp(z_ct[c]) + csI[c];
            if (q == 4 * c + r) { GstR[q] = gpR[c]; GstI[q] = gpI[c]; }  // stage
        }

        // ---- Schur S[q][4c+r] = diag - sum_t ar_t C[t][q] C[t][4c+r] ----
        double accS[4] = {0, 0, 0, 0};
#pragma unroll
        for (int t = 0; t < 16; t++) {
            double w = rld(ar, t) * invDl[t * 17 + q];
#pragma unroll
            for (int c = 0; c < 4; c++) accS[c] += w * invDl[t * 17 + 4 * c + r];
        }
#pragma unroll
        for (int c = 0; c < 4; c++)
            Sst[q * 17 + 4 * c + r] = ((q == 4 * c + r) ? bb[c] : 0.0) - accS[c];

        // ---- load S row q from LDS ----
        double Sr[16];
#pragma unroll
        for (int j2 = 0; j2 < 16; j2++) Sr[j2] = Sst[q * 17 + j2];
        double D0own = Sr[q];

        // ---- 16x16 LDLT in registers (unit-diag L); columns staged to LDS ----
        double invdv = 0.0;   // 1/d_q (own pivot) for the D-divide
#pragma unroll
        for (int kk = 0; kk < 16; kk++) {
            double flo = fmax(1e-12 * fabs(rld(D0own, kk)), 1e-280);
            double dkk = fmax(rld(Sr[kk], kk), flo);
            double inv = drcp(dkk);
            invdv = (q == kk) ? inv : invdv;
            double Lc = Sr[kk] * inv;      // L[q][kk] (unit diag; valid q>=kk)
            if (l < 16) Lst[kk * 17 + l] = Lc;
#pragma unroll
            for (int jj = kk + 1; jj < 16; jj++)
                Sr[jj] -= Sr[kk] * rld(Lc, jj);   // -= (L[q][kk]*d)*L[jj][kk]
            Sr[kk] = Lc;                   // keep L column for the forward solve
        }

        // ---- gather rhs + L^T row from LDS ----
        double y1 = GstR[q], y2 = GstI[q];
        double LTr[16];
#pragma unroll
        for (int kk = 0; kk < 16; kk++) LTr[kk] = Lst[q * 17 + kk];  // L[kk][q]

        // ---- forward solve L w = gp (unit L: no pivot scaling) ----
#pragma unroll
        for (int kk = 0; kk < 16; kk++) {
            double t1 = rld(y1, kk);
            double t2 = rld(y2, kk);
            if (q > kk) { y1 -= Sr[kk] * t1; y2 -= Sr[kk] * t2; }
        }
        // ---- D-divide (lane-local) ----
        y1 *= invdv;
        y2 *= invdv;
        // ---- backward solve L^T qc = v ----
#pragma unroll
        for (int kk = 15; kk >= 0; kk--) {
            double t1 = rld(y1, kk);
            double t2 = rld(y2, kk);
            if (q < kk) { y1 -= LTr[kk] * t1; y2 -= LTr[kk] * t2; }
        }
        // y1,y2 = qc[q] (identical across r-groups)

        // ---- stage qc, gather per own columns ----
        if (l < 16) { QstR[l] = y1; QstI[l] = y2; }
        double qc1c[4], qcvc[4];
#pragma unroll
        for (int c = 0; c < 4; c++) { qc1c[c] = QstR[4 * c + r]; qcvc[c] = QstI[4 * c + r]; }

        // ---- qr = ar*(g_r - sum_j C[q][j] qc_j) (cross4 reduction) ----
        double pr1 = iD[0]*qc1c[0] + iD[1]*qc1c[1] + iD[2]*qc1c[2] + iD[3]*qc1c[3];
        double prv = iD[0]*qcvc[0] + iD[1]*qcvc[1] + iD[2]*qcvc[2] + iD[3]*qcvc[3];
        double qr1 = ar * (rsR - cross4d(pr1));
        double qrv = ar * (rsI - cross4d(prv));

        // ---- u = H^{-1} r1, v = H^{-1} 1 ----
        double u[4], v[4];
#pragma unroll
        for (int c = 0; c < 4; c++) {
            u[c] = (r1[c] - qr1 - qc1c[c]) * iD[c];
            v[c] = (1.0  - qrv - qcvc[c]) * iD[c];
        }
        double usum = sum16d(cross4d(u[0] + u[1] + u[2] + u[3]));
        double vsum = sum16d(cross4d(v[0] + v[1] + v[2] + v[3]));
        double dy = (ra - usum) * drcp(vsum);

        // ---- dx + sums ----
        double dx[4];
#pragma unroll
        for (int c = 0; c < 4; c++) dx[c] = -u[c] - v[c] * dy;
        double rsdx = cross4d(dx[0] + dx[1] + dx[2] + dx[3]);
        double csdx[4];
#pragma unroll
        for (int c = 0; c < 4; c++) csdx[c] = sum16d(dx[c]);
        double sumdx = -usum - vsum * dy;   // sum over all cells of dx (exact identity)

        // ---- ds, dz; SEPARATE primal/dual ratio tests (fp32, 0.99 margin) ----
        float amP = 1e30f, amD = 1e30f;
        double ds[4], dz[4];
#pragma unroll
        for (int c = 0; c < 4; c++) {
            ds[c] = dx[c] - rp[c];
            dz[c] = -(rs[c] + z[c] * ds[c]) * is_[c];
            if (ds[c] < 0.0) amP = fminf(amP, (float)s[c] * frcpf((float)(-ds[c])));
            if (dz[c] < 0.0) amD = fminf(amD, (float)z[c] * frcpf((float)(-dz[c])));
        }
        double ds_rt = -rp_rt - rsdx;
        double dz_rt = -(rs_rt + z_rt * ds_rt) * is_rt;
        if (ds_rt < 0.0) amP = fminf(amP, (float)s_rt * frcpf((float)(-ds_rt)));
        if (dz_rt < 0.0) amD = fminf(amD, (float)z_rt * frcpf((float)(-dz_rt)));
        double ds_ct[4], dz_ct[4];
#pragma unroll
        for (int c = 0; c < 4; c++) {
            ds_ct[c] = -rp_ct[c] - csdx[c];
            dz_ct[c] = -(rs_ct[c] + z_ct[c] * ds_ct[c]) * is_ct[c];
            if (ds_ct[c] < 0.0) amP = fminf(amP, (float)s_ct[c] * frcpf((float)(-ds_ct[c])));
            if (dz_ct[c] < 0.0) amD = fminf(amD, (float)z_ct[c] * frcpf((float)(-dz_ct[c])));
        }
        float aPf = min16f(cross4minf(amP));
        float aDf = min16f(cross4minf(amD));
        double alphaP = 0.99 * fmin(1.0, (double)aPf);
        double alphaD = 0.99 * fmin(1.0, (double)aDf);
        bool good = ((dy - dy) == 0.0);   // freeze on garbage direction
        alphaP = good ? alphaP : 0.0;
        alphaD = good ? alphaD : 0.0;

        // ---- step (x,s with alphaP; z,y with alphaD; x-sums incremental) ----
#pragma unroll
        for (int c = 0; c < 4; c++) {
            x[c] += alphaP * dx[c];
            s[c] += alphaP * ds[c];
            z[c] += alphaD * dz[c];
            s_ct[c] += alphaP * ds_ct[c];
            z_ct[c] += alphaD * dz_ct[c];
            cs[c] += alphaP * csdx[c];
        }
        yv += alphaD * dy;
        s_rt += alphaP * ds_rt;
        z_rt += alphaD * dz_rt;
        rsx += alphaP * rsdx;
        ra  += alphaP * sumdx;
    }

    // ---- emd = p.x + |sum w1 - sum w2| ----
    double e = sum16d(cross4d(px[0]*x[0] + px[1]*x[1] + px[2]*x[2] + px[3]*x[3]));
    if (l == 0) out[b] = (float)(e + sE);
}

extern "C" void kernel_launch(void* const* d_in, const int* in_sizes, int n_in,
                              void* d_out, int out_size, void* d_ws, size_t ws_size,
                              hipStream_t stream) {
    const float* jets1 = (const float*)d_in[0];
    const float* jets2 = (const float*)d_in[1];
    float* out = (float*)d_out;
    int B = in_sizes[0] / 48;   // 32
    emd_ip_kernel<<<dim3(B), dim3(64), 0, stream>>>(jets1, jets2, out);
}